// Round 1
// 1173.812 us; speedup vs baseline: 1.0273x; 1.0273x over previous
//
#include <hip/hip_runtime.h>
#include <hip/hip_bf16.h>
#include <math.h>

#define B_    128
#define L_    128
#define DIN   6
#define D_    256
#define H_    8
#define NL_   6
#define NE_   8
#define DFF_  1024
#define NOUT_ 5
#define T_    (B_*L_)      /* 16384 tokens */
#define DK_   32
#define CH_   512          /* DFF chunk for MoE hidden buffer */

typedef unsigned short u16;
typedef __hip_bfloat16 bf16;
typedef __attribute__((ext_vector_type(8))) short short8;
typedef __attribute__((ext_vector_type(8))) unsigned short ushort8v;
typedef __attribute__((ext_vector_type(4))) float floatx4;

// small f32 canon region: x, emb_w, emb_b, wfreq, wphase, rtw, rtb, eb1,
// eb2, ln_g, ln_b, pred_w, pred_b, unc_w, unc_b
__device__ const int S_PRE[16] = {
    0, 98304, 99840, 100096, 100144, 100192, 106336, 106360,
    130936, 137080, 137336, 137592, 138872, 138877, 140157, 140162};
__device__ const int S_SRC[15] = {0,1,2,7,8,9,10,12,14,15,16,17,18,19,20};
#define NSMALL 140162

struct SrcPtrs { const void* p[21]; };

__device__ __forceinline__ float bf2f(u16 u) {
    return __uint_as_float(((unsigned)u) << 16);
}
__device__ __forceinline__ u16 f2bf(float f) {
    union { bf16 b; u16 u; } c; c.b = __float2bfloat16(f); return c.u;
}
__device__ __forceinline__ float gelu_f(float x) {
    return 0.5f * x * (1.0f + erff(x * 0.70710678118654752f));
}

// async global->LDS, 16B per lane. LDS dest is wave-uniform base + lane*16.
__device__ __forceinline__ void gl_lds16(const void* g, void* l) {
    __builtin_amdgcn_global_load_lds(
        (const __attribute__((address_space(1))) unsigned int*)g,
        (__attribute__((address_space(3))) unsigned int*)l,
        16, 0, 0);
}

// ---------------------------------------------------------------------------
// Canonicalize small tensors to f32 (dtype probe: ln_g[0]==0x3F80 iff bf16)
// ---------------------------------------------------------------------------
__global__ __launch_bounds__(256)
void conv_small_kernel(SrcPtrs P, float* __restrict__ dst)
{
    const int i = blockIdx.x * 256 + threadIdx.x;
    if (i >= NSMALL) return;
    int seg = 0;
    #pragma unroll
    for (int s = 1; s < 15; ++s) seg += (i >= S_PRE[s]) ? 1 : 0;
    const int off = i - S_PRE[seg];
    const void* src = P.p[S_SRC[seg]];
    const bool isbf = (((const u16*)P.p[15])[0] == 0x3F80);
    if (isbf) dst[i] = bf2f(((const u16*)src)[off]);
    else      dst[i] = ((const float*)src)[off];
}

// ---------------------------------------------------------------------------
// Weight transpose+cast: dst[z][(n+noff)][k] (bf16, row len KD) = src[z][k][n]
// ---------------------------------------------------------------------------
template<int KD, int ND>
__global__ __launch_bounds__(256)
void transpose_kernel(const void* __restrict__ src, const u16* __restrict__ probe,
                      u16* __restrict__ dst, long dzs, int noff, int total)
{
    const int i = blockIdx.x * 256 + threadIdx.x;
    if (i >= total) return;
    const int z   = i / (KD * ND);
    const int rem = i - z * (KD * ND);
    const int n   = rem / KD;
    const int k   = rem - n * KD;
    const size_t si = (size_t)z * KD * ND + (size_t)k * ND + n;
    const bool isbf = (probe[0] == 0x3F80);
    const float v = isbf ? bf2f(((const u16*)src)[si]) : ((const float*)src)[si];
    dst[(size_t)z * dzs + (size_t)(n + noff) * KD + k] = f2bf(v);
}

// ---------------------------------------------------------------------------
// Embedding (all f32) + bf16 mirror
// ---------------------------------------------------------------------------
__global__ __launch_bounds__(256)
void embed_kernel(const float* __restrict__ x, const float* __restrict__ emb_w,
                  const float* __restrict__ emb_b, float* __restrict__ h,
                  u16* __restrict__ hb)
{
    const int idx = blockIdx.x * 256 + threadIdx.x;
    const int t = idx >> 8;
    const int d = idx & 255;
    float acc = emb_b[d];
    #pragma unroll
    for (int j = 0; j < DIN; ++j)
        acc += x[t * DIN + j] * emb_w[j * D_ + d];
    h[idx]  = acc;
    hb[idx] = f2bf(acc);
}

// ---------------------------------------------------------------------------
// MFMA GEMM, 128x128 tile, 4 waves (each 64x64 via 16x16x32 bf16 MFMA).
// A: bf16 row-major MxK.  W: bf16 W^T [N][K].
// Staging: global_load_lds width=16, linear LDS (As/Bs [128][32], no pad).
//   thread tid: row = tid>>2 (and +64), 16B quarter = tid&3.
//   LDS offset = wave*1024 + lane*16  (matches HW wave-uniform-base rule).
// EPI 0: store bf16 C            (fused QKV)
// EPI 1: C f32 += ; write bf16 mirror hbout  (o-proj residual)
// EPI 2: +bias, gelu -> bf16 at slot row (MoE w1)
// EPI 3: +bias -> f32 store at slot row  (MoE w2 chunk 0)
// EPI 4: f32 += at slot row              (MoE w2 chunk 1)
// GATHER: A row = atok[ebase[z] + row]
// ---------------------------------------------------------------------------
template<int EPI, bool GATHER>
__global__ __launch_bounds__(256)
void mfma_gemm(const u16* __restrict__ A, int lda, int K,
               const u16* __restrict__ Wt, long wzs, int ldwt, int wkoff,
               const float* __restrict__ biasb, long bzs,
               void* __restrict__ CoutV, int ldc, int cshift,
               u16* __restrict__ hbout,
               int Mfixed,
               const int* __restrict__ cnt, const int* __restrict__ ebase,
               const int* __restrict__ atok)
{
    const int z  = blockIdx.z;
    const int M  = cnt ? cnt[z] : Mfixed;
    const int r0 = blockIdx.x * 128;
    if (r0 >= M) return;
    const int rowbase = ebase ? ebase[z] : 0;
    const u16*   W    = Wt + (size_t)z * wzs;
    const float* bias = biasb ? (biasb + (size_t)z * bzs) : nullptr;
    const int col0 = blockIdx.y * 128 + cshift;

    __shared__ __attribute__((aligned(16))) u16 As[128][32];
    __shared__ __attribute__((aligned(16))) u16 Bs[128][32];
    __shared__ int stok[128];

    const int tid  = threadIdx.x;
    const int lane = tid & 63;
    const int wave = tid >> 6;
    const int wm = wave & 1, wn = wave >> 1;

    if (GATHER) {
        if (tid < 128) {
            int rr = r0 + tid;
            stok[tid] = (rr < M) ? atok[rowbase + rr] : 0;
        }
        __syncthreads();
    }

    // staging addresses (loop-invariant part)
    const int srow = tid >> 2;          // 0..63
    const int sq   = tid & 3;           // 16B quarter within the 64B row
    long ar0, ar1;
    if (GATHER) {
        ar0 = stok[srow];
        ar1 = stok[srow + 64];
    } else {
        int rr0 = r0 + srow;      if (rr0 >= M) rr0 = M - 1;
        int rr1 = r0 + srow + 64; if (rr1 >= M) rr1 = M - 1;
        ar0 = (long)rowbase + rr0;
        ar1 = (long)rowbase + rr1;
    }
    const u16* ga0 = A + ar0 * (long)lda + sq * 8;
    const u16* ga1 = A + ar1 * (long)lda + sq * 8;
    const u16* gb0 = W + (size_t)(col0 + srow)      * ldwt + wkoff + sq * 8;
    const u16* gb1 = W + (size_t)(col0 + srow + 64) * ldwt + wkoff + sq * 8;
    u16* lA0 = &As[wave * 16][0];
    u16* lA1 = &As[64 + wave * 16][0];
    u16* lB0 = &Bs[wave * 16][0];
    u16* lB1 = &Bs[64 + wave * 16][0];

    floatx4 acc[4][4];
    #pragma unroll
    for (int i = 0; i < 4; ++i)
        #pragma unroll
        for (int j = 0; j < 4; ++j)
            acc[i][j] = (floatx4){0.f, 0.f, 0.f, 0.f};

    const int fm = wm * 64 + (lane & 15);
    const int fn = wn * 64 + (lane & 15);
    const int fk = (lane >> 4) * 8;

    for (int k0 = 0; k0 < K; k0 += 32) {
        gl_lds16(ga0 + k0, lA0);
        gl_lds16(ga1 + k0, lA1);
        gl_lds16(gb0 + k0, lB0);
        gl_lds16(gb1 + k0, lB1);
        __syncthreads();              // drains vmcnt: LDS tiles landed

        short8 af[4], bfr[4];
        #pragma unroll
        for (int i = 0; i < 4; ++i) af[i]  = *(const short8*)&As[fm + 16*i][fk];
        #pragma unroll
        for (int j = 0; j < 4; ++j) bfr[j] = *(const short8*)&Bs[fn + 16*j][fk];
        #pragma unroll
        for (int i = 0; i < 4; ++i)
            #pragma unroll
            for (int j = 0; j < 4; ++j)
                acc[i][j] = __builtin_amdgcn_mfma_f32_16x16x32_bf16(
                    af[i], bfr[j], acc[i][j], 0, 0, 0);
        __syncthreads();
    }

    const int er = wm * 64 + ((lane >> 4) << 2);
    const int ec = wn * 64 + (lane & 15);
    #pragma unroll
    for (int i = 0; i < 4; ++i) {
        #pragma unroll
        for (int reg = 0; reg < 4; ++reg) {
            const int grow = r0 + er + i * 16 + reg;
            if (grow >= M) continue;
            #pragma unroll
            for (int j = 0; j < 4; ++j) {
                const int cj = col0 + ec + j * 16;
                const int cl = cj - cshift;
                const float val = acc[i][j][reg];
                if constexpr (EPI == 0) {
                    ((u16*)CoutV)[(size_t)grow * ldc + cl] = f2bf(val);
                } else if constexpr (EPI == 1) {
                    const size_t idx = (size_t)grow * ldc + cl;
                    const float nv = ((float*)CoutV)[idx] + val;
                    ((float*)CoutV)[idx] = nv;
                    hbout[idx] = f2bf(nv);
                } else if constexpr (EPI == 2) {
                    ((u16*)CoutV)[(size_t)(rowbase + grow) * ldc + cl] =
                        f2bf(gelu_f(val + bias[cj]));
                } else if constexpr (EPI == 3) {
                    ((float*)CoutV)[(size_t)(rowbase + grow) * ldc + cl] =
                        val + bias[cj];
                } else {
                    ((float*)CoutV)[(size_t)(rowbase + grow) * ldc + cl] += val;
                }
            }
        }
    }
}

// ---------------------------------------------------------------------------
// MFMA wave attention, one block (256 thr, 4 waves) per (b, head).
// ---------------------------------------------------------------------------
__global__ __launch_bounds__(256)
void attn_kernel(const u16* __restrict__ qkv, u16* __restrict__ o,
                 const float* __restrict__ wfreq, const float* __restrict__ wphase)
{
    const int bh = blockIdx.x;
    const int b  = bh >> 3;
    const int hh = bh & 7;

    __shared__ __attribute__((aligned(16))) u16 Qs[128][40];
    __shared__ __attribute__((aligned(16))) u16 Ks[128][40];
    __shared__ __attribute__((aligned(16))) u16 Vt[32][136];
    __shared__ __attribute__((aligned(16))) u16 Ps[128][136];
    __shared__ float wavec[128];

    const int tid  = threadIdx.x;
    const int lane = tid & 63;
    const int w    = tid >> 6;
    const int col16 = lane & 15;
    const int quad  = lane >> 4;

    const long qbase = (long)b * L_ * 768 + hh * DK_;

    // stage Q, K, V^T (bf16)
    {
        const int row = tid >> 1;
        const int hf  = (tid & 1) * 16;
        const u16* src = qkv + qbase + (long)row * 768 + hf;
        *(ushort8v*)&Qs[row][hf]     = *(const ushort8v*)(src);
        *(ushort8v*)&Qs[row][hf + 8] = *(const ushort8v*)(src + 8);
        *(ushort8v*)&Ks[row][hf]     = *(const ushort8v*)(src + 256);
        *(ushort8v*)&Ks[row][hf + 8] = *(const ushort8v*)(src + 264);
        #pragma unroll
        for (int j = 0; j < 16; ++j)
            Vt[hf + j][row] = src[512 + j];
    }
    if (tid < L_) {
        float f2 = 6.2831853071795864769f * wfreq[hh];
        wavec[tid] = cosf(f2 * (float)tid + wphase[hh]);
    }
    __syncthreads();

    const float scale = 0.17677669529663687f;   // 1/sqrt(32)
    float wv8[8];
    #pragma unroll
    for (int ni = 0; ni < 8; ++ni)
        wv8[ni] = scale * wavec[ni * 16 + col16];

    // S = Q K^T : wave w owns rows [w*32, w*32+32)
    const int m0 = w * 32;
    floatx4 accs[2][8];
    {
        short8 a0 = *(const short8*)&Qs[m0 + col16][quad * 8];
        short8 a1 = *(const short8*)&Qs[m0 + 16 + col16][quad * 8];
        #pragma unroll
        for (int ni = 0; ni < 8; ++ni) {
            short8 bf = *(const short8*)&Ks[ni * 16 + col16][quad * 8];
            accs[0][ni] = __builtin_amdgcn_mfma_f32_16x16x32_bf16(
                a0, bf, (floatx4){0.f,0.f,0.f,0.f}, 0, 0, 0);
            accs[1][ni] = __builtin_amdgcn_mfma_f32_16x16x32_bf16(
                a1, bf, (floatx4){0.f,0.f,0.f,0.f}, 0, 0, 0);
        }
    }
    #pragma unroll
    for (int mi = 0; mi < 2; ++mi)
        #pragma unroll
        for (int ni = 0; ni < 8; ++ni)
            #pragma unroll
            for (int reg = 0; reg < 4; ++reg)
                accs[mi][ni][reg] *= wv8[ni];

    // full-row softmax: row = m0 + mi*16 + quad*4 + reg, in-wave
    #pragma unroll
    for (int mi = 0; mi < 2; ++mi) {
        #pragma unroll
        for (int reg = 0; reg < 4; ++reg) {
            float rmax = -1e30f;
            #pragma unroll
            for (int ni = 0; ni < 8; ++ni)
                rmax = fmaxf(rmax, accs[mi][ni][reg]);
            #pragma unroll
            for (int off = 1; off < 16; off <<= 1)
                rmax = fmaxf(rmax, __shfl_xor(rmax, off));
            float e[8], rsum = 0.0f;
            #pragma unroll
            for (int ni = 0; ni < 8; ++ni) {
                e[ni] = expf(accs[mi][ni][reg] - rmax);
                rsum += e[ni];
            }
            #pragma unroll
            for (int off = 1; off < 16; off <<= 1)
                rsum += __shfl_xor(rsum, off);
            const float inv = 1.0f / rsum;
            const int row = m0 + mi * 16 + quad * 4 + reg;
            #pragma unroll
            for (int ni = 0; ni < 8; ++ni)
                Ps[row][ni * 16 + col16] = f2bf(e[ni] * inv);
        }
    }
    __syncthreads();

    // O = P V
    floatx4 acco[2][2];
    #pragma unroll
    for (int mi = 0; mi < 2; ++mi)
        #pragma unroll
        for (int nj = 0; nj < 2; ++nj)
            acco[mi][nj] = (floatx4){0.f,0.f,0.f,0.f};
    #pragma unroll
    for (int kk = 0; kk < 4; ++kk) {
        short8 a0 = *(const short8*)&Ps[m0 + col16][kk * 32 + quad * 8];
        short8 a1 = *(const short8*)&Ps[m0 + 16 + col16][kk * 32 + quad * 8];
        short8 b0 = *(const short8*)&Vt[col16][kk * 32 + quad * 8];
        short8 b1 = *(const short8*)&Vt[16 + col16][kk * 32 + quad * 8];
        acco[0][0] = __builtin_amdgcn_mfma_f32_16x16x32_bf16(a0, b0, acco[0][0], 0, 0, 0);
        acco[0][1] = __builtin_amdgcn_mfma_f32_16x16x32_bf16(a0, b1, acco[0][1], 0, 0, 0);
        acco[1][0] = __builtin_amdgcn_mfma_f32_16x16x32_bf16(a1, b0, acco[1][0], 0, 0, 0);
        acco[1][1] = __builtin_amdgcn_mfma_f32_16x16x32_bf16(a1, b1, acco[1][1], 0, 0, 0);
    }

    const long obase = (long)b * L_ * D_ + hh * DK_;
    #pragma unroll
    for (int mi = 0; mi < 2; ++mi)
        #pragma unroll
        for (int reg = 0; reg < 4; ++reg) {
            const int row = m0 + mi * 16 + quad * 4 + reg;
            #pragma unroll
            for (int nj = 0; nj < 2; ++nj)
                o[obase + (long)row * D_ + nj * 16 + col16] =
                    f2bf(acco[mi][nj][reg]);
        }
}

// ---------------------------------------------------------------------------
// MoE router: one WAVE per token.
// ---------------------------------------------------------------------------
__global__ __launch_bounds__(256)
void router_kernel(const float* __restrict__ h, const float* __restrict__ rtw,
                   const float* __restrict__ rtb, int* __restrict__ te,
                   float* __restrict__ twt)
{
    const int tid  = threadIdx.x;
    const int lane = tid & 63;
    const int wv   = tid >> 6;
    const int t    = blockIdx.x * 4 + wv;

    const float4 hv = ((const float4*)(h + (long)t * D_))[lane];
    const float4* rp = (const float4*)rtw;

    float lg[NE_];
    #pragma unroll
    for (int e = 0; e < NE_; ++e) lg[e] = 0.0f;
    #pragma unroll
    for (int i = 0; i < 4; ++i) {
        const int d = lane * 4 + i;
        const float xv = (i == 0) ? hv.x : (i == 1) ? hv.y : (i == 2) ? hv.z : hv.w;
        float4 wa = rp[d * 2 + 0];
        float4 wb = rp[d * 2 + 1];
        lg[0] = fmaf(xv, wa.x, lg[0]);
        lg[1] = fmaf(xv, wa.y, lg[1]);
        lg[2] = fmaf(xv, wa.z, lg[2]);
        lg[3] = fmaf(xv, wa.w, lg[3]);
        lg[4] = fmaf(xv, wb.x, lg[4]);
        lg[5] = fmaf(xv, wb.y, lg[5]);
        lg[6] = fmaf(xv, wb.z, lg[6]);
        lg[7] = fmaf(xv, wb.w, lg[7]);
    }
    #pragma unroll
    for (int off = 1; off < 64; off <<= 1)
        #pragma unroll
        for (int e = 0; e < NE_; ++e)
            lg[e] += __shfl_xor(lg[e], off);

    if (lane == 0) {
        #pragma unroll
        for (int e = 0; e < NE_; ++e) lg[e] += rtb[e];
        int i1 = 0; float v1 = lg[0];
        #pragma unroll
        for (int e = 1; e < NE_; ++e) { if (lg[e] > v1) { v1 = lg[e]; i1 = e; } }
        int i2 = (i1 == 0) ? 1 : 0; float v2 = lg[i2];
        #pragma unroll
        for (int e = 0; e < NE_; ++e) {
            if (e != i1 && lg[e] > v2) { v2 = lg[e]; i2 = e; }
        }
        float r   = expf(v2 - v1);
        float wa1 = 1.0f / (1.0f + r);
        te[2 * t]     = i1;
        te[2 * t + 1] = i2;
        twt[2 * t]     = wa1;
        twt[2 * t + 1] = r * wa1;
    }
}

// ---------------------------------------------------------------------------
// Count experts + exclusive scan + zero cursors, single block of 512.
// ---------------------------------------------------------------------------
__global__ __launch_bounds__(512)
void countscan_kernel(const int* __restrict__ te, int* __restrict__ cnt,
                      int* __restrict__ base_, int* __restrict__ cursor)
{
    const int tid = threadIdx.x;
    int c[NE_];
    #pragma unroll
    for (int e = 0; e < NE_; ++e) c[e] = 0;
    for (int i = tid; i < 2 * T_; i += 512) {
        const int e = te[i];
        #pragma unroll
        for (int ee = 0; ee < NE_; ++ee) c[ee] += (e == ee) ? 1 : 0;
    }
    #pragma unroll
    for (int off = 1; off < 64; off <<= 1)
        #pragma unroll
        for (int e = 0; e < NE_; ++e)
            c[e] += __shfl_xor(c[e], off);

    __shared__ int wsum[8][NE_];
    const int lane = tid & 63, wv = tid >> 6;
    if (lane == 0)
        #pragma unroll
        for (int e = 0; e < NE_; ++e) wsum[wv][e] = c[e];
    __syncthreads();
    if (tid == 0) {
        int a = 0;
        for (int e = 0; e < NE_; ++e) {
            int s = 0;
            for (int w = 0; w < 8; ++w) s += wsum[w][e];
            cnt[e] = s;
            base_[e] = a;
            a += s;
        }
    }
    if (tid < NE_) cursor[tid] = 0;
}

// ---------------------------------------------------------------------------
// Scatter with LDS rank aggregation: 8 global atomics per block.
// ---------------------------------------------------------------------------
__global__ __launch_bounds__(256)
void scatter_kernel(const int* __restrict__ te, const int* __restrict__ base_,
                    int* __restrict__ cursor, int* __restrict__ atok,
                    int* __restrict__ tslot)
{
    __shared__ int lcnt[NE_];
    __shared__ int gb[NE_];
    const int tid = threadIdx.x;
    if (tid < NE_) lcnt[tid] = 0;
    __syncthreads();

    const int i0 = blockIdx.x * 512 + tid * 2;
    const int e0 = te[i0], e1 = te[i0 + 1];
    const int r0 = atomicAdd(&lcnt[e0], 1);
    const int r1 = atomicAdd(&lcnt[e1], 1);
    __syncthreads();
    if (tid < NE_) gb[tid] = atomicAdd(&cursor[tid], lcnt[tid]);
    __syncthreads();

    const int s0 = base_[e0] + gb[e0] + r0;
    const int s1 = base_[e1] + gb[e1] + r1;
    atok[s0] = i0 >> 1;
    atok[s1] = i0 >> 1;
    tslot[i0]     = s0;
    tslot[i0 + 1] = s1;
}

// h[t][d] += twt[2t]*eo[tslot[2t]][d] + twt[2t+1]*eo[tslot[2t+1]][d]; mirror bf16
__global__ __launch_bounds__(256)
void combine_kernel(float* __restrict__ h, u16* __restrict__ hb,
                    const float* __restrict__ eo,
                    const float* __restrict__ twt, const int* __restrict__ tslot)
{
    const int t = blockIdx.x;
    const int d = threadIdx.x;
    const int s0 = tslot[2 * t], s1 = tslot[2 * t + 1];
    const float w0 = twt[2 * t], w1 = twt[2 * t + 1];
    const long idx = (long)t * D_ + d;
    const float nv = h[idx] + w0 * eo[(long)s0 * D_ + d] + w1 * eo[(long)s1 * D_ + d];
    h[idx]  = nv;
    hb[idx] = f2bf(nv);
}

// ---------------------------------------------------------------------------
// Final: LN on last-position tokens, pred / softplus heads. f32 output.
// ---------------------------------------------------------------------------
__global__ __launch_bounds__(256)
void final_kernel(const float* __restrict__ h, const float* __restrict__ ln_g,
                  const float* __restrict__ ln_b, const float* __restrict__ pred_w,
                  const float* __restrict__ pred_b, const float* __restrict__ unc_w,
                  const float* __restrict__ unc_b, float* __restrict__ out)
{
    const int b = blockIdx.x;
    const int d = threadIdx.x;
    const long t = (long)b * L_ + (L_ - 1);
    const float val = h[t * D_ + d];

    __shared__ float red[4];
    __shared__ float lat[D_];

    float s = val;
    #pragma unroll
    for (int off = 32; off > 0; off >>= 1) s += __shfl_down(s, off);
    if ((d & 63) == 0) red[d >> 6] = s;
    __syncthreads();
    const float mean = (red[0] + red[1] + red[2] + red[3]) * (1.0f / D_);
    __syncthreads();

    const float dv = val - mean;
    s = dv * dv;
    #pragma unroll
    for (int off = 32; off > 0; off >>= 1) s += __shfl_down(s, off);
    if ((d & 63) == 0) red[d >> 6] = s;
    __syncthreads();
    const float var = (red[0] + red[1] + red[2] + red[3]) * (1.0f / D_);

    lat[d] = dv * rsqrtf(var + 1e-5f) * ln_g[d] + ln_b[d];
    __syncthreads();

    if (d < 2 * NOUT_) {
        const int j = d % NOUT_;
        const int sel = d / NOUT_;
        const float* w  = sel ? unc_w : pred_w;
        const float* bb = sel ? unc_b : pred_b;
        float acc = bb[j];
        for (int dd = 0; dd < D_; ++dd)
            acc = fmaf(lat[dd], w[dd * NOUT_ + j], acc);
        if (sel) acc = log1pf(expf(acc));
        out[sel * (B_ * NOUT_) + b * NOUT_ + j] = acc;
    }
}

// ---------------------------------------------------------------------------
extern "C" void kernel_launch(void* const* d_in, const int* in_sizes, int n_in,
                              void* d_out, int out_size, void* d_ws, size_t ws_size,
                              hipStream_t stream)
{
    (void)in_sizes; (void)n_in; (void)out_size; (void)ws_size;

    char* ws = (char*)d_ws;
    size_t off = 0;
    auto alloc = [&](size_t bytes) {
        size_t cur = off;
        off += (bytes + 255) & ~(size_t)255;
        return (void*)(ws + cur);
    };
    float* cs     = (float*)alloc((size_t)NSMALL * 4);
    u16*   qkvt   = (u16*)  alloc((size_t)NL_ * 768 * 256 * 2);
    u16*   wot    = (u16*)  alloc((size_t)NL_ * 256 * 256 * 2);
    u16*   ew1t   = (u16*)  alloc((size_t)3 * NE_ * DFF_ * D_ * 2);
    u16*   ew2t   = (u16*)  alloc((size_t)3 * NE_ * D_ * DFF_ * 2);
    float* h      = (float*)alloc((size_t)T_ * D_ * 4);
    u16*   hb     = (u16*)  alloc((size_t)T_ * D_ * 2);
    u16*   qkvb   = (u16*)  alloc((size_t)T_ * 768 * 2);
    u16*   ob     = (u16*)  alloc((size_t)T_ * D_ * 2);
    u16*   hidden = (u16*)  alloc((size_t)2 * T_ * CH_ * 2);
    float* eo     = (float*)alloc((size_t)2 * T_ * D_ * 4);
    int*   te     = (int*)  alloc((size_t)2 * T_ * 4);
    float* twt    = (float*)alloc((size_t)2 * T_ * 4);
    int*   atok   = (int*)  alloc((size_t)2 * T_ * 4);
    int*   tslot  = (int*)  alloc((size_t)2 * T_ * 4);
    int*   cnt    = (int*)  alloc(64 * 4);
    int*   base_  = (int*)  alloc(64 * 4);
    int*   cursor = (int*)  alloc(64 * 4);

    SrcPtrs P;
    for (int i = 0; i < 21; ++i) P.p[i] = d_in[i];
    const u16* probe = (const u16*)d_in[15];

    conv_small_kernel<<<(NSMALL + 255) / 256, 256, 0, stream>>>(P, cs);
    transpose_kernel<256,256><<<(NL_*65536 + 255)/256, 256, 0, stream>>>(
        d_in[3], probe, qkvt, 768L*256, 0,   NL_*65536);
    transpose_kernel<256,256><<<(NL_*65536 + 255)/256, 256, 0, stream>>>(
        d_in[4], probe, qkvt, 768L*256, 256, NL_*65536);
    transpose_kernel<256,256><<<(NL_*65536 + 255)/256, 256, 0, stream>>>(
        d_in[5], probe, qkvt, 768L*256, 512, NL_*65536);
    transpose_kernel<256,256><<<(NL_*65536 + 255)/256, 256, 0, stream>>>(
        d_in[6], probe, wot, 65536L, 0, NL_*65536);
    transpose_kernel<256,1024><<<(24*262144 + 255)/256, 256, 0, stream>>>(
        d_in[11], probe, ew1t, 262144L, 0, 24*262144);
    transpose_kernel<1024,256><<<(24*262144 + 255)/256, 256, 0, stream>>>(
        d_in[13], probe, ew2t, 262144L, 0, 24*262144);

    const float* x      = cs;
    const float* emb_w  = cs + 98304;
    const float* emb_b  = cs + 99840;
    const float* wfreq  = cs + 100096;
    const float* wphase = cs + 100144;
    const float* rtw    = cs + 100192;
    const float* rtb    = cs + 106336;
    const float* eb1    = cs + 106360;
    const float* eb2    = cs + 130936;
    const float* ln_g   = cs + 137080;
    const float* ln_b   = cs + 137336;
    const float* pred_w = cs + 137592;
    const float* pred_b = cs + 138872;
    const float* unc_w  = cs + 138877;
    const float* unc_b  = cs + 140157;

    embed_kernel<<<(T_ * D_) / 256, 256, 0, stream>>>(x, emb_w, emb_b, h, hb);

    for (int i = 0; i < NL_; ++i) {
        mfma_gemm<0, false><<<dim3(T_/128, 6, 1), 256, 0, stream>>>(
            hb, D_, D_, qkvt + (size_t)i * 768 * 256, 0, 256, 0,
            nullptr, 0, qkvb, 768, 0, nullptr, T_, nullptr, nullptr, nullptr);
        attn_kernel<<<B_ * H_, 256, 0, stream>>>(qkvb, ob,
                                                 wfreq + i * H_, wphase + i * H_);
        mfma_gemm<1, false><<<dim3(T_/128, 2, 1), 256, 0, stream>>>(
            ob, D_, D_, wot + (size_t)i * 65536, 0, 256, 0,
            nullptr, 0, h, D_, 0, hb, T_, nullptr, nullptr, nullptr);

        if (i % 2 == 0) {
            const int m = i / 2;
            const u16* w1t = ew1t + (size_t)m * NE_ * DFF_ * D_;
            const u16* w2t = ew2t + (size_t)m * NE_ * D_ * DFF_;
            const float* b1 = eb1 + (size_t)m * NE_ * DFF_;
            const float* b2 = eb2 + (size_t)m * NE_ * D_;
            router_kernel<<<T_ / 4, 256, 0, stream>>>(
                h, rtw + (size_t)m * D_ * NE_, rtb + m * NE_, te, twt);
            countscan_kernel<<<1, 512, 0, stream>>>(te, cnt, base_, cursor);
            scatter_kernel<<<(2 * T_) / 512, 256, 0, stream>>>(te, base_, cursor,
                                                               atok, tslot);
            for (int c = 0; c < DFF_ / CH_; ++c) {
                mfma_gemm<2, true><<<dim3(128, CH_/128, NE_), 256, 0, stream>>>(
                    hb, D_, D_, w1t, (long)DFF_ * D_, 256, 0,
                    b1, DFF_, hidden, CH_, c * CH_,
                    nullptr, 0, cnt, base_, atok);
                if (c == 0)
                    mfma_gemm<3, false><<<dim3(128, 2, NE_), 256, 0, stream>>>(
                        hidden, CH_, CH_, w2t, (long)D_ * DFF_, DFF_, c * CH_,
                        b2, D_, eo, D_, 0,
                        nullptr, 0, cnt, base_, nullptr);
                else
                    mfma_gemm<4, false><<<dim3(128, 2, NE_), 256, 0, stream>>>(
                        hidden, CH_, CH_, w2t, (long)D_ * DFF_, DFF_, c * CH_,
                        nullptr, 0, eo, D_, 0,
                        nullptr, 0, cnt, base_, nullptr);
            }
            combine_kernel<<<T_, 256, 0, stream>>>(h, hb, eo, twt, tslot);
        }
    }

    final_kernel<<<B_, 256, 0, stream>>>(h, ln_g, ln_b, pred_w, pred_b,
                                         unc_w, unc_b, (float*)d_out);
}

// Round 2
// 1012.230 us; speedup vs baseline: 1.1913x; 1.1596x over previous
//
#include <hip/hip_runtime.h>
#include <hip/hip_bf16.h>
#include <math.h>

#define B_    128
#define L_    128
#define DIN   6
#define D_    256
#define H_    8
#define NL_   6
#define NE_   8
#define DFF_  1024
#define NOUT_ 5
#define T_    (B_*L_)      /* 16384 tokens */
#define DK_   32
#define NDESC_MAX 264      /* 32768/128 + 8 experts worst-case ceil slack */

typedef unsigned short u16;
typedef __hip_bfloat16 bf16;
typedef __attribute__((ext_vector_type(8))) short short8;
typedef __attribute__((ext_vector_type(8))) unsigned short ushort8v;
typedef __attribute__((ext_vector_type(4))) float floatx4;

// small f32 canon region: x, emb_w, emb_b, wfreq, wphase, rtw, rtb, eb1,
// eb2, ln_g, ln_b, pred_w, pred_b, unc_w, unc_b
__device__ const int S_PRE[16] = {
    0, 98304, 99840, 100096, 100144, 100192, 106336, 106360,
    130936, 137080, 137336, 137592, 138872, 138877, 140157, 140162};
__device__ const int S_SRC[15] = {0,1,2,7,8,9,10,12,14,15,16,17,18,19,20};
#define NSMALL 140162

struct SrcPtrs { const void* p[21]; };

__device__ __forceinline__ float bf2f(u16 u) {
    return __uint_as_float(((unsigned)u) << 16);
}
__device__ __forceinline__ u16 f2bf(float f) {
    union { bf16 b; u16 u; } c; c.b = __float2bfloat16(f); return c.u;
}
__device__ __forceinline__ float gelu_f(float x) {
    return 0.5f * x * (1.0f + erff(x * 0.70710678118654752f));
}

// ---------------------------------------------------------------------------
// Canonicalize small tensors to f32 (dtype probe: ln_g[0]==0x3F80 iff bf16)
// ---------------------------------------------------------------------------
__global__ __launch_bounds__(256)
void conv_small_kernel(SrcPtrs P, float* __restrict__ dst)
{
    const int i = blockIdx.x * 256 + threadIdx.x;
    if (i >= NSMALL) return;
    int seg = 0;
    #pragma unroll
    for (int s = 1; s < 15; ++s) seg += (i >= S_PRE[s]) ? 1 : 0;
    const int off = i - S_PRE[seg];
    const void* src = P.p[S_SRC[seg]];
    const bool isbf = (((const u16*)P.p[15])[0] == 0x3F80);
    if (isbf) dst[i] = bf2f(((const u16*)src)[off]);
    else      dst[i] = ((const float*)src)[off];
}

// ---------------------------------------------------------------------------
// Weight transpose+cast: dst[z][(n+noff)][k] (bf16, row len KD) = src[z][k][n]
// ---------------------------------------------------------------------------
template<int KD, int ND>
__global__ __launch_bounds__(256)
void transpose_kernel(const void* __restrict__ src, const u16* __restrict__ probe,
                      u16* __restrict__ dst, long dzs, int noff, int total)
{
    const int i = blockIdx.x * 256 + threadIdx.x;
    if (i >= total) return;
    const int z   = i / (KD * ND);
    const int rem = i - z * (KD * ND);
    const int n   = rem / KD;
    const int k   = rem - n * KD;
    const size_t si = (size_t)z * KD * ND + (size_t)k * ND + n;
    const bool isbf = (probe[0] == 0x3F80);
    const float v = isbf ? bf2f(((const u16*)src)[si]) : ((const float*)src)[si];
    dst[(size_t)z * dzs + (size_t)(n + noff) * KD + k] = f2bf(v);
}

// ---------------------------------------------------------------------------
// Embedding (all f32) + bf16 mirror
// ---------------------------------------------------------------------------
__global__ __launch_bounds__(256)
void embed_kernel(const float* __restrict__ x, const float* __restrict__ emb_w,
                  const float* __restrict__ emb_b, float* __restrict__ h,
                  u16* __restrict__ hb)
{
    const int idx = blockIdx.x * 256 + threadIdx.x;
    const int t = idx >> 8;
    const int d = idx & 255;
    float acc = emb_b[d];
    #pragma unroll
    for (int j = 0; j < DIN; ++j)
        acc += x[t * DIN + j] * emb_w[j * D_ + d];
    h[idx]  = acc;
    hb[idx] = f2bf(acc);
}

// ---------------------------------------------------------------------------
// MFMA GEMM, 128x128 tile, 4 waves (each 64x64 via 16x16x32 bf16 MFMA).
// A: bf16 row-major.  W: bf16 W^T [N][K].
// Staging: reg-prefetch (t+1 loads issued before MFMAs of t), double-buffered
// padded LDS ([2][128][40], ~2-way bank aliasing = free), ONE barrier/K-step.
// MODE 0: dense rows (Mfixed), block row tile = blockIdx.x*128
// MODE 1: descriptor-driven, A row gathered via atok (MoE w1)
// MODE 2: descriptor-driven, A row = slot (MoE w2)
// EPI 0: store bf16 C                         (fused QKV)
// EPI 1: C f32 += ; bf16 mirror hbout         (o-proj residual)
// EPI 2: +bias, gelu -> bf16                  (MoE w1)
// EPI 3: +bias -> f32 store                   (MoE w2)
// ---------------------------------------------------------------------------
template<int EPI, int MODE>
__global__ __launch_bounds__(256)
void mfma_gemm(const u16* __restrict__ A, int lda, int K,
               const u16* __restrict__ Wt, long wzs, int ldwt,
               const float* __restrict__ biasb, long bzs,
               void* __restrict__ CoutV, int ldc,
               u16* __restrict__ hbout, int Mfixed,
               const int* __restrict__ cnt, const int* __restrict__ base_,
               const int* __restrict__ atok,
               const int* __restrict__ de, const int* __restrict__ dr,
               const int* __restrict__ ndesc)
{
    int M, r0, sbase = 0, e = 0;
    if constexpr (MODE == 0) {
        M  = Mfixed;
        r0 = blockIdx.x * 128;
        if (r0 >= M) return;
    } else {
        const int i = blockIdx.x;
        if (i >= *ndesc) return;
        e     = de[i];
        r0    = dr[i] * 128;
        sbase = base_[e];
        M     = cnt[e];
    }
    const u16*   W    = Wt + (size_t)e * wzs;
    const float* bias = biasb ? (biasb + (size_t)e * bzs) : nullptr;
    const int col0 = blockIdx.y * 128;

    __shared__ __attribute__((aligned(16))) u16 As[2][128][40];
    __shared__ __attribute__((aligned(16))) u16 Bs[2][128][40];
    __shared__ int stok[128];

    const int tid  = threadIdx.x;
    const int lane = tid & 63;
    const int wave = tid >> 6;
    const int wm = wave & 1, wn = wave >> 1;

    if constexpr (MODE == 1) {
        if (tid < 128) {
            int rr = r0 + tid;
            if (rr >= M) rr = M - 1;
            stok[tid] = atok[sbase + rr];
        }
        __syncthreads();
    }

    // staging: 2 threads per row, each covers 32B (16 u16) of the 64B row
    const int srow = tid >> 1;          // 0..127
    const int sk   = (tid & 1) * 16;
    long arow;
    if constexpr (MODE == 1) {
        arow = stok[srow];
    } else {
        int rr = r0 + srow;
        if (rr >= M) rr = M - 1;
        arow = (MODE == 2) ? (long)(sbase + rr) : (long)rr;
    }
    const u16* ga = A + arow * (long)lda + sk;
    const u16* gw = W + (size_t)(col0 + srow) * ldwt + sk;

    floatx4 acc[4][4];
    #pragma unroll
    for (int i = 0; i < 4; ++i)
        #pragma unroll
        for (int j = 0; j < 4; ++j)
            acc[i][j] = (floatx4){0.f, 0.f, 0.f, 0.f};

    const int fm = wm * 64 + (lane & 15);
    const int fn = wn * 64 + (lane & 15);
    const int fk = (lane >> 4) * 8;

    // prologue loads (tile 0)
    ushort8v ra0 = *(const ushort8v*)(ga);
    ushort8v ra1 = *(const ushort8v*)(ga + 8);
    ushort8v rb0 = *(const ushort8v*)(gw);
    ushort8v rb1 = *(const ushort8v*)(gw + 8);

    const int nt = K >> 5;
    int buf = 0;
    for (int t = 0; t < nt; ++t) {
        *(ushort8v*)&As[buf][srow][sk]     = ra0;
        *(ushort8v*)&As[buf][srow][sk + 8] = ra1;
        *(ushort8v*)&Bs[buf][srow][sk]     = rb0;
        *(ushort8v*)&Bs[buf][srow][sk + 8] = rb1;
        __syncthreads();     // one barrier per K-step (double buffer)

        if (t + 1 < nt) {    // prefetch t+1 into regs; overlaps the MFMAs
            const int k0 = (t + 1) << 5;
            ra0 = *(const ushort8v*)(ga + k0);
            ra1 = *(const ushort8v*)(ga + k0 + 8);
            rb0 = *(const ushort8v*)(gw + k0);
            rb1 = *(const ushort8v*)(gw + k0 + 8);
        }

        short8 af[4], bfr[4];
        #pragma unroll
        for (int i = 0; i < 4; ++i) af[i]  = *(const short8*)&As[buf][fm + 16*i][fk];
        #pragma unroll
        for (int j = 0; j < 4; ++j) bfr[j] = *(const short8*)&Bs[buf][fn + 16*j][fk];
        #pragma unroll
        for (int i = 0; i < 4; ++i)
            #pragma unroll
            for (int j = 0; j < 4; ++j)
                acc[i][j] = __builtin_amdgcn_mfma_f32_16x16x32_bf16(
                    af[i], bfr[j], acc[i][j], 0, 0, 0);
        buf ^= 1;
    }

    const int er = wm * 64 + ((lane >> 4) << 2);
    const int ec = wn * 64 + (lane & 15);
    #pragma unroll
    for (int i = 0; i < 4; ++i) {
        #pragma unroll
        for (int reg = 0; reg < 4; ++reg) {
            const int lrow = r0 + er + i * 16 + reg;
            if (lrow >= M) continue;
            const long crow = (MODE == 0) ? (long)lrow : (long)(sbase + lrow);
            #pragma unroll
            for (int j = 0; j < 4; ++j) {
                const int cj = col0 + ec + j * 16;
                const float val = acc[i][j][reg];
                if constexpr (EPI == 0) {
                    ((u16*)CoutV)[crow * ldc + cj] = f2bf(val);
                } else if constexpr (EPI == 1) {
                    const size_t idx = crow * ldc + cj;
                    const float nv = ((float*)CoutV)[idx] + val;
                    ((float*)CoutV)[idx] = nv;
                    hbout[idx] = f2bf(nv);
                } else if constexpr (EPI == 2) {
                    ((u16*)CoutV)[crow * ldc + cj] = f2bf(gelu_f(val + bias[cj]));
                } else {
                    ((float*)CoutV)[crow * ldc + cj] = val + bias[cj];
                }
            }
        }
    }
}

// ---------------------------------------------------------------------------
// MFMA wave attention, one block (256 thr, 4 waves) per (b, head).
// ---------------------------------------------------------------------------
__global__ __launch_bounds__(256)
void attn_kernel(const u16* __restrict__ qkv, u16* __restrict__ o,
                 const float* __restrict__ wfreq, const float* __restrict__ wphase)
{
    const int bh = blockIdx.x;
    const int b  = bh >> 3;
    const int hh = bh & 7;

    __shared__ __attribute__((aligned(16))) u16 Qs[128][40];
    __shared__ __attribute__((aligned(16))) u16 Ks[128][40];
    __shared__ __attribute__((aligned(16))) u16 Vt[32][136];
    __shared__ __attribute__((aligned(16))) u16 Ps[128][136];
    __shared__ float wavec[128];

    const int tid  = threadIdx.x;
    const int lane = tid & 63;
    const int w    = tid >> 6;
    const int col16 = lane & 15;
    const int quad  = lane >> 4;

    const long qbase = (long)b * L_ * 768 + hh * DK_;

    // stage Q, K, V^T (bf16)
    {
        const int row = tid >> 1;
        const int hf  = (tid & 1) * 16;
        const u16* src = qkv + qbase + (long)row * 768 + hf;
        *(ushort8v*)&Qs[row][hf]     = *(const ushort8v*)(src);
        *(ushort8v*)&Qs[row][hf + 8] = *(const ushort8v*)(src + 8);
        *(ushort8v*)&Ks[row][hf]     = *(const ushort8v*)(src + 256);
        *(ushort8v*)&Ks[row][hf + 8] = *(const ushort8v*)(src + 264);
        #pragma unroll
        for (int j = 0; j < 16; ++j)
            Vt[hf + j][row] = src[512 + j];
    }
    if (tid < L_) {
        float f2 = 6.2831853071795864769f * wfreq[hh];
        wavec[tid] = cosf(f2 * (float)tid + wphase[hh]);
    }
    __syncthreads();

    const float scale = 0.17677669529663687f;   // 1/sqrt(32)
    float wv8[8];
    #pragma unroll
    for (int ni = 0; ni < 8; ++ni)
        wv8[ni] = scale * wavec[ni * 16 + col16];

    // S = Q K^T : wave w owns rows [w*32, w*32+32)
    const int m0 = w * 32;
    floatx4 accs[2][8];
    {
        short8 a0 = *(const short8*)&Qs[m0 + col16][quad * 8];
        short8 a1 = *(const short8*)&Qs[m0 + 16 + col16][quad * 8];
        #pragma unroll
        for (int ni = 0; ni < 8; ++ni) {
            short8 bf = *(const short8*)&Ks[ni * 16 + col16][quad * 8];
            accs[0][ni] = __builtin_amdgcn_mfma_f32_16x16x32_bf16(
                a0, bf, (floatx4){0.f,0.f,0.f,0.f}, 0, 0, 0);
            accs[1][ni] = __builtin_amdgcn_mfma_f32_16x16x32_bf16(
                a1, bf, (floatx4){0.f,0.f,0.f,0.f}, 0, 0, 0);
        }
    }
    #pragma unroll
    for (int mi = 0; mi < 2; ++mi)
        #pragma unroll
        for (int ni = 0; ni < 8; ++ni)
            #pragma unroll
            for (int reg = 0; reg < 4; ++reg)
                accs[mi][ni][reg] *= wv8[ni];

    // full-row softmax: row = m0 + mi*16 + quad*4 + reg, in-wave
    #pragma unroll
    for (int mi = 0; mi < 2; ++mi) {
        #pragma unroll
        for (int reg = 0; reg < 4; ++reg) {
            float rmax = -1e30f;
            #pragma unroll
            for (int ni = 0; ni < 8; ++ni)
                rmax = fmaxf(rmax, accs[mi][ni][reg]);
            #pragma unroll
            for (int off = 1; off < 16; off <<= 1)
                rmax = fmaxf(rmax, __shfl_xor(rmax, off));
            float e[8], rsum = 0.0f;
            #pragma unroll
            for (int ni = 0; ni < 8; ++ni) {
                e[ni] = expf(accs[mi][ni][reg] - rmax);
                rsum += e[ni];
            }
            #pragma unroll
            for (int off = 1; off < 16; off <<= 1)
                rsum += __shfl_xor(rsum, off);
            const float inv = 1.0f / rsum;
            const int row = m0 + mi * 16 + quad * 4 + reg;
            #pragma unroll
            for (int ni = 0; ni < 8; ++ni)
                Ps[row][ni * 16 + col16] = f2bf(e[ni] * inv);
        }
    }
    __syncthreads();

    // O = P V
    floatx4 acco[2][2];
    #pragma unroll
    for (int mi = 0; mi < 2; ++mi)
        #pragma unroll
        for (int nj = 0; nj < 2; ++nj)
            acco[mi][nj] = (floatx4){0.f,0.f,0.f,0.f};
    #pragma unroll
    for (int kk = 0; kk < 4; ++kk) {
        short8 a0 = *(const short8*)&Ps[m0 + col16][kk * 32 + quad * 8];
        short8 a1 = *(const short8*)&Ps[m0 + 16 + col16][kk * 32 + quad * 8];
        short8 b0 = *(const short8*)&Vt[col16][kk * 32 + quad * 8];
        short8 b1 = *(const short8*)&Vt[16 + col16][kk * 32 + quad * 8];
        acco[0][0] = __builtin_amdgcn_mfma_f32_16x16x32_bf16(a0, b0, acco[0][0], 0, 0, 0);
        acco[0][1] = __builtin_amdgcn_mfma_f32_16x16x32_bf16(a0, b1, acco[0][1], 0, 0, 0);
        acco[1][0] = __builtin_amdgcn_mfma_f32_16x16x32_bf16(a1, b0, acco[1][0], 0, 0, 0);
        acco[1][1] = __builtin_amdgcn_mfma_f32_16x16x32_bf16(a1, b1, acco[1][1], 0, 0, 0);
    }

    const long obase = (long)b * L_ * D_ + hh * DK_;
    #pragma unroll
    for (int mi = 0; mi < 2; ++mi)
        #pragma unroll
        for (int reg = 0; reg < 4; ++reg) {
            const int row = m0 + mi * 16 + quad * 4 + reg;
            #pragma unroll
            for (int nj = 0; nj < 2; ++nj)
                o[obase + (long)row * D_ + nj * 16 + col16] =
                    f2bf(acco[mi][nj][reg]);
        }
}

// ---------------------------------------------------------------------------
// MoE router: one WAVE per token.
// ---------------------------------------------------------------------------
__global__ __launch_bounds__(256)
void router_kernel(const float* __restrict__ h, const float* __restrict__ rtw,
                   const float* __restrict__ rtb, int* __restrict__ te,
                   float* __restrict__ twt)
{
    const int tid  = threadIdx.x;
    const int lane = tid & 63;
    const int wv   = tid >> 6;
    const int t    = blockIdx.x * 4 + wv;

    const float4 hv = ((const float4*)(h + (long)t * D_))[lane];
    const float4* rp = (const float4*)rtw;

    float lg[NE_];
    #pragma unroll
    for (int e = 0; e < NE_; ++e) lg[e] = 0.0f;
    #pragma unroll
    for (int i = 0; i < 4; ++i) {
        const int d = lane * 4 + i;
        const float xv = (i == 0) ? hv.x : (i == 1) ? hv.y : (i == 2) ? hv.z : hv.w;
        float4 wa = rp[d * 2 + 0];
        float4 wb = rp[d * 2 + 1];
        lg[0] = fmaf(xv, wa.x, lg[0]);
        lg[1] = fmaf(xv, wa.y, lg[1]);
        lg[2] = fmaf(xv, wa.z, lg[2]);
        lg[3] = fmaf(xv, wa.w, lg[3]);
        lg[4] = fmaf(xv, wb.x, lg[4]);
        lg[5] = fmaf(xv, wb.y, lg[5]);
        lg[6] = fmaf(xv, wb.z, lg[6]);
        lg[7] = fmaf(xv, wb.w, lg[7]);
    }
    #pragma unroll
    for (int off = 1; off < 64; off <<= 1)
        #pragma unroll
        for (int e = 0; e < NE_; ++e)
            lg[e] += __shfl_xor(lg[e], off);

    if (lane == 0) {
        #pragma unroll
        for (int e = 0; e < NE_; ++e) lg[e] += rtb[e];
        int i1 = 0; float v1 = lg[0];
        #pragma unroll
        for (int e = 1; e < NE_; ++e) { if (lg[e] > v1) { v1 = lg[e]; i1 = e; } }
        int i2 = (i1 == 0) ? 1 : 0; float v2 = lg[i2];
        #pragma unroll
        for (int e = 0; e < NE_; ++e) {
            if (e != i1 && lg[e] > v2) { v2 = lg[e]; i2 = e; }
        }
        float r   = expf(v2 - v1);
        float wa1 = 1.0f / (1.0f + r);
        te[2 * t]     = i1;
        te[2 * t + 1] = i2;
        twt[2 * t]     = wa1;
        twt[2 * t + 1] = r * wa1;
    }
}

// ---------------------------------------------------------------------------
// Count experts + exclusive scan + zero cursors + tile descriptors.
// ---------------------------------------------------------------------------
__global__ __launch_bounds__(512)
void countscan_kernel(const int* __restrict__ te, int* __restrict__ cnt,
                      int* __restrict__ base_, int* __restrict__ cursor,
                      int* __restrict__ de, int* __restrict__ dr,
                      int* __restrict__ ndesc)
{
    const int tid = threadIdx.x;
    int c[NE_];
    #pragma unroll
    for (int e = 0; e < NE_; ++e) c[e] = 0;
    for (int i = tid; i < 2 * T_; i += 512) {
        const int e = te[i];
        #pragma unroll
        for (int ee = 0; ee < NE_; ++ee) c[ee] += (e == ee) ? 1 : 0;
    }
    #pragma unroll
    for (int off = 1; off < 64; off <<= 1)
        #pragma unroll
        for (int e = 0; e < NE_; ++e)
            c[e] += __shfl_xor(c[e], off);

    __shared__ int wsum[8][NE_];
    const int lane = tid & 63, wv = tid >> 6;
    if (lane == 0)
        #pragma unroll
        for (int e = 0; e < NE_; ++e) wsum[wv][e] = c[e];
    __syncthreads();
    if (tid == 0) {
        int a = 0, n = 0;
        for (int e = 0; e < NE_; ++e) {
            int s = 0;
            for (int w = 0; w < 8; ++w) s += wsum[w][e];
            cnt[e] = s;
            base_[e] = a;
            a += s;
            const int nb = (s + 127) >> 7;
            for (int rb = 0; rb < nb; ++rb) {
                de[n] = e; dr[n] = rb; ++n;
            }
        }
        *ndesc = n;
    }
    if (tid < NE_) cursor[tid] = 0;
}

// ---------------------------------------------------------------------------
// Scatter with LDS rank aggregation: 8 global atomics per block.
// ---------------------------------------------------------------------------
__global__ __launch_bounds__(256)
void scatter_kernel(const int* __restrict__ te, const int* __restrict__ base_,
                    int* __restrict__ cursor, int* __restrict__ atok,
                    int* __restrict__ tslot)
{
    __shared__ int lcnt[NE_];
    __shared__ int gb[NE_];
    const int tid = threadIdx.x;
    if (tid < NE_) lcnt[tid] = 0;
    __syncthreads();

    const int i0 = blockIdx.x * 512 + tid * 2;
    const int e0 = te[i0], e1 = te[i0 + 1];
    const int r0 = atomicAdd(&lcnt[e0], 1);
    const int r1 = atomicAdd(&lcnt[e1], 1);
    __syncthreads();
    if (tid < NE_) gb[tid] = atomicAdd(&cursor[tid], lcnt[tid]);
    __syncthreads();

    const int s0 = base_[e0] + gb[e0] + r0;
    const int s1 = base_[e1] + gb[e1] + r1;
    atok[s0] = i0 >> 1;
    atok[s1] = i0 >> 1;
    tslot[i0]     = s0;
    tslot[i0 + 1] = s1;
}

// h[t][d] += twt[2t]*eo[tslot[2t]][d] + twt[2t+1]*eo[tslot[2t+1]][d]; mirror bf16
__global__ __launch_bounds__(256)
void combine_kernel(float* __restrict__ h, u16* __restrict__ hb,
                    const float* __restrict__ eo,
                    const float* __restrict__ twt, const int* __restrict__ tslot)
{
    const int t = blockIdx.x;
    const int d = threadIdx.x;
    const int s0 = tslot[2 * t], s1 = tslot[2 * t + 1];
    const float w0 = twt[2 * t], w1 = twt[2 * t + 1];
    const long idx = (long)t * D_ + d;
    const float nv = h[idx] + w0 * eo[(long)s0 * D_ + d] + w1 * eo[(long)s1 * D_ + d];
    h[idx]  = nv;
    hb[idx] = f2bf(nv);
}

// ---------------------------------------------------------------------------
// Final: LN on last-position tokens, pred / softplus heads. f32 output.
// ---------------------------------------------------------------------------
__global__ __launch_bounds__(256)
void final_kernel(const float* __restrict__ h, const float* __restrict__ ln_g,
                  const float* __restrict__ ln_b, const float* __restrict__ pred_w,
                  const float* __restrict__ pred_b, const float* __restrict__ unc_w,
                  const float* __restrict__ unc_b, float* __restrict__ out)
{
    const int b = blockIdx.x;
    const int d = threadIdx.x;
    const long t = (long)b * L_ + (L_ - 1);
    const float val = h[t * D_ + d];

    __shared__ float red[4];
    __shared__ float lat[D_];

    float s = val;
    #pragma unroll
    for (int off = 32; off > 0; off >>= 1) s += __shfl_down(s, off);
    if ((d & 63) == 0) red[d >> 6] = s;
    __syncthreads();
    const float mean = (red[0] + red[1] + red[2] + red[3]) * (1.0f / D_);
    __syncthreads();

    const float dv = val - mean;
    s = dv * dv;
    #pragma unroll
    for (int off = 32; off > 0; off >>= 1) s += __shfl_down(s, off);
    if ((d & 63) == 0) red[d >> 6] = s;
    __syncthreads();
    const float var = (red[0] + red[1] + red[2] + red[3]) * (1.0f / D_);

    lat[d] = dv * rsqrtf(var + 1e-5f) * ln_g[d] + ln_b[d];
    __syncthreads();

    if (d < 2 * NOUT_) {
        const int j = d % NOUT_;
        const int sel = d / NOUT_;
        const float* w  = sel ? unc_w : pred_w;
        const float* bb = sel ? unc_b : pred_b;
        float acc = bb[j];
        for (int dd = 0; dd < D_; ++dd)
            acc = fmaf(lat[dd], w[dd * NOUT_ + j], acc);
        if (sel) acc = log1pf(expf(acc));
        out[sel * (B_ * NOUT_) + b * NOUT_ + j] = acc;
    }
}

// ---------------------------------------------------------------------------
extern "C" void kernel_launch(void* const* d_in, const int* in_sizes, int n_in,
                              void* d_out, int out_size, void* d_ws, size_t ws_size,
                              hipStream_t stream)
{
    (void)in_sizes; (void)n_in; (void)out_size; (void)ws_size;

    char* ws = (char*)d_ws;
    size_t off = 0;
    auto alloc = [&](size_t bytes) {
        size_t cur = off;
        off += (bytes + 255) & ~(size_t)255;
        return (void*)(ws + cur);
    };
    float* cs     = (float*)alloc((size_t)NSMALL * 4);
    u16*   qkvt   = (u16*)  alloc((size_t)NL_ * 768 * 256 * 2);
    u16*   wot    = (u16*)  alloc((size_t)NL_ * 256 * 256 * 2);
    u16*   ew1t   = (u16*)  alloc((size_t)3 * NE_ * DFF_ * D_ * 2);
    u16*   ew2t   = (u16*)  alloc((size_t)3 * NE_ * D_ * DFF_ * 2);
    float* h      = (float*)alloc((size_t)T_ * D_ * 4);
    u16*   hb     = (u16*)  alloc((size_t)T_ * D_ * 2);
    // union region: attn-phase {qkvb, ob} aliases moe-phase {hidden, eo}
    // (disjoint lifetimes within a layer; see launch order)
    char*  uni    = (char*) alloc((size_t)2 * T_ * DFF_ * 2 + (size_t)2 * T_ * D_ * 4);
    u16*   qkvb   = (u16*)  uni;                                    // 25.2 MB
    u16*   ob     = (u16*)  (uni + (size_t)T_ * 768 * 2 + 256);     //  8.4 MB
    u16*   hidden = (u16*)  uni;                                    // 67.1 MB
    float* eo     = (float*)(uni + (size_t)2 * T_ * DFF_ * 2);      // 33.6 MB
    int*   te     = (int*)  alloc((size_t)2 * T_ * 4);
    float* twt    = (float*)alloc((size_t)2 * T_ * 4);
    int*   atok   = (int*)  alloc((size_t)2 * T_ * 4);
    int*   tslot  = (int*)  alloc((size_t)2 * T_ * 4);
    int*   cnt    = (int*)  alloc(64 * 4);
    int*   base_  = (int*)  alloc(64 * 4);
    int*   cursor = (int*)  alloc(64 * 4);
    int*   de     = (int*)  alloc(NDESC_MAX * 4);
    int*   dr     = (int*)  alloc(NDESC_MAX * 4);
    int*   ndesc  = (int*)  alloc(64 * 4);

    SrcPtrs P;
    for (int i = 0; i < 21; ++i) P.p[i] = d_in[i];
    const u16* probe = (const u16*)d_in[15];

    conv_small_kernel<<<(NSMALL + 255) / 256, 256, 0, stream>>>(P, cs);
    transpose_kernel<256,256><<<(NL_*65536 + 255)/256, 256, 0, stream>>>(
        d_in[3], probe, qkvt, 768L*256, 0,   NL_*65536);
    transpose_kernel<256,256><<<(NL_*65536 + 255)/256, 256, 0, stream>>>(
        d_in[4], probe, qkvt, 768L*256, 256, NL_*65536);
    transpose_kernel<256,256><<<(NL_*65536 + 255)/256, 256, 0, stream>>>(
        d_in[5], probe, qkvt, 768L*256, 512, NL_*65536);
    transpose_kernel<256,256><<<(NL_*65536 + 255)/256, 256, 0, stream>>>(
        d_in[6], probe, wot, 65536L, 0, NL_*65536);
    transpose_kernel<256,1024><<<(24*262144 + 255)/256, 256, 0, stream>>>(
        d_in[11], probe, ew1t, 262144L, 0, 24*262144);
    transpose_kernel<1024,256><<<(24*262144 + 255)/256, 256, 0, stream>>>(
        d_in[13], probe, ew2t, 262144L, 0, 24*262144);

    const float* x      = cs;
    const float* emb_w  = cs + 98304;
    const float* emb_b  = cs + 99840;
    const float* wfreq  = cs + 100096;
    const float* wphase = cs + 100144;
    const float* rtw    = cs + 100192;
    const float* rtb    = cs + 106336;
    const float* eb1    = cs + 106360;
    const float* eb2    = cs + 130936;
    const float* ln_g   = cs + 137080;
    const float* ln_b   = cs + 137336;
    const float* pred_w = cs + 137592;
    const float* pred_b = cs + 138872;
    const float* unc_w  = cs + 138877;
    const float* unc_b  = cs + 140157;

    embed_kernel<<<(T_ * D_) / 256, 256, 0, stream>>>(x, emb_w, emb_b, h, hb);

    for (int i = 0; i < NL_; ++i) {
        // QKV: [16384 x 768] = hb[16384 x 256] @ qkvt^T
        mfma_gemm<0, 0><<<dim3(T_/128, 6, 1), 256, 0, stream>>>(
            hb, D_, D_, qkvt + (size_t)i * 768 * 256, 0, 256,
            nullptr, 0, qkvb, 768, nullptr, T_,
            nullptr, nullptr, nullptr, nullptr, nullptr, nullptr);
        attn_kernel<<<B_ * H_, 256, 0, stream>>>(qkvb, ob,
                                                 wfreq + i * H_, wphase + i * H_);
        // o-proj + residual
        mfma_gemm<1, 0><<<dim3(T_/128, 2, 1), 256, 0, stream>>>(
            ob, D_, D_, wot + (size_t)i * 65536, 0, 256,
            nullptr, 0, h, D_, hb, T_,
            nullptr, nullptr, nullptr, nullptr, nullptr, nullptr);

        if (i % 2 == 0) {
            const int m = i / 2;
            const u16* w1t = ew1t + (size_t)m * NE_ * DFF_ * D_;
            const u16* w2t = ew2t + (size_t)m * NE_ * D_ * DFF_;
            const float* b1 = eb1 + (size_t)m * NE_ * DFF_;
            const float* b2 = eb2 + (size_t)m * NE_ * D_;
            router_kernel<<<T_ / 4, 256, 0, stream>>>(
                h, rtw + (size_t)m * D_ * NE_, rtb + m * NE_, te, twt);
            countscan_kernel<<<1, 512, 0, stream>>>(te, cnt, base_, cursor,
                                                    de, dr, ndesc);
            scatter_kernel<<<(2 * T_) / 512, 256, 0, stream>>>(te, base_, cursor,
                                                               atok, tslot);
            // w1 fused over full DFF: hidden[slot][1024] = gelu(hb[tok] @ w1 + b1)
            mfma_gemm<2, 1><<<dim3(NDESC_MAX, DFF_/128, 1), 256, 0, stream>>>(
                hb, D_, D_, w1t, (long)DFF_ * D_, 256,
                b1, DFF_, hidden, DFF_, nullptr, 0,
                cnt, base_, atok, de, dr, ndesc);
            // w2 fused over full K=1024: eo[slot][256] = hidden[slot] @ w2 + b2
            mfma_gemm<3, 2><<<dim3(NDESC_MAX, D_/128, 1), 256, 0, stream>>>(
                hidden, DFF_, DFF_, w2t, (long)D_ * DFF_, DFF_,
                b2, D_, eo, D_, nullptr, 0,
                cnt, base_, nullptr, de, dr, ndesc);
            combine_kernel<<<T_, 256, 0, stream>>>(h, hb, eo, twt, tslot);
        }
    }

    final_kernel<<<B_, 256, 0, stream>>>(h, ln_g, ln_b, pred_w, pred_b,
                                         unc_w, unc_b, (float*)d_out);
}